// Round 5
// baseline (411.997 us; speedup 1.0000x reference)
//
#include <hip/hip_runtime.h>
#include <hip/hip_bf16.h>
#include <stdint.h>

#define D_    1024
#define L_    2048
#define B_    4
#define NHEAD 8
#define HDIM  128
#define BL_   (B_*L_)   // 8192
#define EPS_  1e-6f

typedef __attribute__((ext_vector_type(8))) short short8;
typedef __attribute__((ext_vector_type(4))) float f32x4;

__device__ __forceinline__ unsigned short f2bf(float f) {
  unsigned u = __builtin_bit_cast(unsigned, f);
  unsigned r = 0x7fffu + ((u >> 16) & 1u);
  return (unsigned short)((u + r) >> 16);
}
__device__ __forceinline__ float bf2f(unsigned short h) {
  return __builtin_bit_cast(float, ((unsigned)h) << 16);
}
__device__ __forceinline__ float silu_f(float x) { return x / (1.f + __expf(-x)); }

// async global->LDS, 16B per lane; LDS dest is wave-uniform base + lane*16
__device__ __forceinline__ void gll16(const void* g, void* l) {
  auto gp = reinterpret_cast<const __attribute__((address_space(1))) unsigned*>(
      reinterpret_cast<uintptr_t>(g));
  auto lp = reinterpret_cast<__attribute__((address_space(3))) unsigned*>(
      (unsigned)reinterpret_cast<uintptr_t>(l));
  __builtin_amdgcn_global_load_lds(gp, lp, 16, 0, 0);
}

// ---------------- weight transpose + cast: w[1024][1024] f32 -> wt[1024][1024] bf16 (wt = w^T)
__global__ __launch_bounds__(256) void wt_kernel(
    const float* __restrict__ wu, const float* __restrict__ wq,
    const float* __restrict__ wk, const float* __restrict__ wv,
    const float* __restrict__ wo, unsigned short* __restrict__ wt)
{
  __shared__ float t[64][65];
  int mat = blockIdx.z;
  const float* src = mat==0?wu: mat==1?wq: mat==2?wk: mat==3?wv: wo;
  unsigned short* dst = wt + (size_t)mat*D_*D_;
  int r0 = blockIdx.y*64, c0 = blockIdx.x*64;
  int tid = threadIdx.x;
  for (int i = 0; i < 16; ++i) {
    int e = i*256 + tid; int r = e>>6, c = e&63;
    t[r][c] = src[(size_t)(r0+r)*D_ + c0 + c];
  }
  __syncthreads();
  for (int i = 0; i < 16; ++i) {
    int e = i*256 + tid; int r = e>>6, c = e&63;
    dst[(size_t)(c0+r)*D_ + r0 + c] = f2bf(t[c][r]);
  }
}

// ---------------- input LN -> bf16 x
__global__ __launch_bounds__(256) void ln_in_kernel(
    const float* __restrict__ in, const float* __restrict__ gamma,
    const float* __restrict__ beta, unsigned short* __restrict__ x)
{
  int row = blockIdx.x, tid = threadIdx.x;
  float4 v = ((const float4*)(in + (size_t)row*D_))[tid];
  float s = v.x+v.y+v.z+v.w;
  float ss = v.x*v.x + v.y*v.y + v.z*v.z + v.w*v.w;
  #pragma unroll
  for (int o = 32; o; o >>= 1) { s += __shfl_down(s,o); ss += __shfl_down(ss,o); }
  __shared__ float red[8];
  int lane = tid&63, wid = tid>>6;
  if (lane==0) { red[wid]=s; red[4+wid]=ss; }
  __syncthreads();
  s = red[0]+red[1]+red[2]+red[3];
  ss = red[4]+red[5]+red[6]+red[7];
  float mean = s * (1.f/D_);
  float var  = ss * (1.f/D_) - mean*mean;
  float rstd = rsqrtf(var + EPS_);
  float4 g = ((const float4*)gamma)[tid], b = ((const float4*)beta)[tid];
  ushort4 o;
  o.x = f2bf((v.x-mean)*rstd*g.x + b.x);
  o.y = f2bf((v.y-mean)*rstd*g.y + b.y);
  o.z = f2bf((v.z-mean)*rstd*g.z + b.z);
  o.w = f2bf((v.w-mean)*rstd*g.w + b.w);
  ((ushort4*)(x + (size_t)row*D_))[tid] = o;
}

// ---------------- 256x(BN) phased GEMM, C = A[M][1024] * Bt[cols][1024]^T
// 8 waves (WM x WN), BK=32 per phase, 4-slice LDS ring (2 K-tiles), counted vmcnt.
// Per phase: 12 ds_read_b128 + stage-next-slice gll16 + barrier + lgkmcnt(0) +
//            setprio(1) + MF*4 MFMA + setprio(0) + vmcnt(counted) + barrier.
// Ring invariant: phase g stages slice for phase g+3 into region (g+3)&3, which was
// fully consumed at phase g-1 (lgkmcnt(0) before that phase's MFMA + closing barrier).
// vmcnt(2*LPP) at phase end drains the 3-phase-old loads before the next phase reads.
// MODE 0: BN=256, silu epilogue -> u/q/k bf16 + v transposed; MODE 1: BN=128, acc+resid f32.
template<int MODE>
__global__ __launch_bounds__(512, 2) void gemm8p(
    const unsigned short* __restrict__ A, const unsigned short* __restrict__ Bt,
    unsigned short* __restrict__ o_u, unsigned short* __restrict__ o_q,
    unsigned short* __restrict__ o_k, unsigned short* __restrict__ o_vt,
    const float* __restrict__ resid, float* __restrict__ o_f)
{
  constexpr int BN  = (MODE==0) ? 256 : 128;
  constexpr int WN  = (MODE==0) ? 4 : 2;       // waves along N
  constexpr int WTM = (MODE==0) ? 128 : 64;    // wave tile rows (256/WM)
  constexpr int MF  = WTM/16;                  // m-frags per wave: 8 or 4
  constexpr int BNS = BN*32;                   // B slice ushorts (BK=32)
  constexpr int BOFF = 32768;                  // A region: 4 slices * 8192
  constexpr int RG  = BN/64;                   // row-groups per kk8 in B slice
  constexpr int NBW = RG/ (64/64) * 4 / 8 * 2; // B chunks per wave = (BN*32/512)/8
  // NBW: MODE0 -> 16/8=2, MODE1 -> 8/8=1
  constexpr int NBCHW = (BNS/512)/8;
  const int K = 1024;

  __shared__ unsigned short lds[BOFF + 4*BNS];

  int lane = threadIdx.x & 63, wid = threadIdx.x >> 6;
  int wr = wid / WN, wc = wid % WN;
  int m0 = blockIdx.x * 256;
  int n0 = blockIdx.y * BN;
  const unsigned short* Ab = A + (size_t)m0*K;
  const unsigned short* Bb = Bt + (size_t)n0*K;

  f32x4 acc[MF][4] = {};

  auto stage = [&](int dbs, int k0) {
    #pragma unroll
    for (int j = 0; j < 2; ++j) {
      int c = wid*2 + j;                 // 16 A chunks
      int row = (c&3)*64 + lane;
      int kof = k0 + ((c>>2)<<3);
      gll16(Ab + (size_t)row*K + kof, &lds[dbs*8192 + c*512]);
    }
    #pragma unroll
    for (int j = 0; j < NBCHW; ++j) {
      int c = wid*NBCHW + j;             // BNS/512 B chunks
      int kk8 = c / RG, rg = c % RG;
      int row = rg*64 + lane;
      int kof = k0 + (kk8<<3);
      gll16(Bb + (size_t)row*K + kof, &lds[BOFF + dbs*BNS + c*512]);
    }
  };

  // prologue: stage phases 0..3 (K-tiles 0,1), wait for phase 0's slice
  #pragma unroll
  for (int gp = 0; gp < 4; ++gp) stage(gp, gp*32);
  if constexpr (MODE==0) asm volatile("s_waitcnt vmcnt(12)" ::: "memory");
  else                   asm volatile("s_waitcnt vmcnt(9)"  ::: "memory");
  __builtin_amdgcn_s_barrier();

  auto do_phase = [&](int g, bool dostage) {
    const int bs = g & 3;
    const int kk4 = lane>>4, l15 = lane&15;
    short8 af[MF], bfr[4];
    const int ab = bs*8192 + kk4*2048 + (wr*WTM + l15)*8;
    #pragma unroll
    for (int m = 0; m < MF; ++m) af[m] = *(const short8*)&lds[ab + m*128];
    const int bb = BOFF + bs*BNS + kk4*(BN*8) + (wc*64 + l15)*8;
    #pragma unroll
    for (int n = 0; n < 4; ++n) bfr[n] = *(const short8*)&lds[bb + n*128];
    if (dostage) {
      int tp = g + 3;
      int k0 = (tp < 32 ? tp : 31) * 32;   // clamp SOURCE only; dest region stays tp&3
      stage(tp & 3, k0);
    }
    __builtin_amdgcn_sched_barrier(0);
    __builtin_amdgcn_s_barrier();
    asm volatile("s_waitcnt lgkmcnt(0)" ::: "memory");
    __builtin_amdgcn_sched_barrier(0);
    __builtin_amdgcn_s_setprio(1);
    #pragma unroll
    for (int m = 0; m < MF; ++m)
      #pragma unroll
      for (int n = 0; n < 4; ++n)
        acc[m][n] = __builtin_amdgcn_mfma_f32_16x16x32_bf16(af[m], bfr[n], acc[m][n], 0,0,0);
    __builtin_amdgcn_s_setprio(0);
    if constexpr (MODE==0) asm volatile("s_waitcnt vmcnt(8)" ::: "memory");
    else                   asm volatile("s_waitcnt vmcnt(6)" ::: "memory");
    __builtin_amdgcn_sched_barrier(0);
    __builtin_amdgcn_s_barrier();
  };

  do_phase(0, false);
  #pragma unroll
  for (int g = 1; g < 32; ++g) do_phase(g, true);

  if constexpr (MODE == 0) {
    int mat = n0 >> 10;
    int jb = n0 & 1023;
    #pragma unroll
    for (int m = 0; m < MF; ++m) {
      int t_ = m0 + wr*WTM + m*16 + ((lane>>4)<<2);
      #pragma unroll
      for (int n = 0; n < 4; ++n) {
        int jj = jb + wc*64 + n*16 + (lane&15);
        float p0 = silu_f(acc[m][n][0]);
        float p1 = silu_f(acc[m][n][1]);
        float p2 = silu_f(acc[m][n][2]);
        float p3 = silu_f(acc[m][n][3]);
        if (mat == 3) {
          int b = t_ >> 11, tt = t_ & 2047;
          int nn = jj >> 7, h = jj & 127;
          ushort4 pk;
          pk.x = f2bf(p0); pk.y = f2bf(p1); pk.z = f2bf(p2); pk.w = f2bf(p3);
          *(ushort4*)&o_vt[(((size_t)(b*NHEAD+nn))*HDIM + h)*L_ + tt] = pk;
        } else {
          unsigned short* dst = mat==0 ? o_u : (mat==1 ? o_q : o_k);
          dst[(size_t)(t_+0)*D_ + jj] = f2bf(p0);
          dst[(size_t)(t_+1)*D_ + jj] = f2bf(p1);
          dst[(size_t)(t_+2)*D_ + jj] = f2bf(p2);
          dst[(size_t)(t_+3)*D_ + jj] = f2bf(p3);
        }
      }
    }
  } else {
    #pragma unroll
    for (int m = 0; m < MF; ++m) {
      int t_ = m0 + wr*WTM + m*16 + ((lane>>4)<<2);
      #pragma unroll
      for (int n = 0; n < 4; ++n) {
        int jj = n0 + wc*64 + n*16 + (lane&15);
        #pragma unroll
        for (int r = 0; r < 4; ++r)
          o_f[(size_t)(t_+r)*D_ + jj] = acc[m][n][r] + resid[(size_t)(t_+r)*D_ + jj];
      }
    }
  }
}

// ---------------- causal pointwise-silu attention
// one t-tile (128 rows) per block; grid 16x32 = 512 blocks -> 2 blocks/CU co-resident
// S^T = K*Q^T computed so P packs into LDS in A-fragment layout; O += P*V with pre-transposed V
__global__ __launch_bounds__(256, 2) void attn_kernel(
    const unsigned short* __restrict__ gq, const unsigned short* __restrict__ gk,
    const unsigned short* __restrict__ gvt, unsigned short* __restrict__ attn_out)
{
  __shared__ unsigned short KP[16384];  // K tile / P tile: [x/8][128][8]
  __shared__ unsigned short VT[16384];  // V^T tile: [s/8][h(128)][8]
  int bh = blockIdx.y;
  int b = bh >> 3, n = bh & 7;
  const unsigned short* qb = gq + (size_t)b*L_*D_ + n*HDIM;
  const unsigned short* kb = gk + (size_t)b*L_*D_ + n*HDIM;
  const unsigned short* vb = gvt + (size_t)bh*HDIM*L_;
  unsigned short* ob = attn_out + (size_t)b*L_*D_ + n*HDIM;
  int lane = threadIdx.x & 63, wid = threadIdx.x >> 6;
  int wr = wid >> 1, wc = wid & 1;

  int ti = blockIdx.x;
  int t0 = ti * 128;
  // stage Q tile into KP, hoist B-fragments to registers
  #pragma unroll
  for (int i = 0; i < 8; ++i) {
    int c = wid*8 + i;
    int row = ((c&1)<<6) + lane;
    int kof = (c>>1)<<3;
    gll16(qb + (size_t)(t0+row)*D_ + kof, &KP[c*512]);
  }
  __syncthreads();
  short8 qf[4][4];
  #pragma unroll
  for (int kk = 0; kk < 4; ++kk) {
    int kbase = (kk*4 + (lane>>4))*1024;
    #pragma unroll
    for (int fn = 0; fn < 4; ++fn)
      qf[kk][fn] = *(const short8*)&KP[kbase + (wc*64 + fn*16 + (lane&15))*8];
  }
  __syncthreads();
  f32x4 oacc[4][4] = {};
  for (int st = 0; st <= ti; ++st) {
    int s0 = st*128;
    #pragma unroll
    for (int i = 0; i < 8; ++i) {
      int c = wid*8 + i;
      int row = ((c&1)<<6) + lane;
      int kof = (c>>1)<<3;
      gll16(kb + (size_t)(s0+row)*D_ + kof, &KP[c*512]);
      gll16(vb + (size_t)row*L_ + s0 + kof, &VT[c*512]);
    }
    __syncthreads();
    // S^T[s][t] = sum_h K[s][h] Q[t][h]
    f32x4 sacc[4][4] = {};
    #pragma unroll
    for (int kk = 0; kk < 4; ++kk) {
      int kbase = (kk*4 + (lane>>4))*1024;
      short8 kf[4];
      #pragma unroll
      for (int fm = 0; fm < 4; ++fm)
        kf[fm] = *(const short8*)&KP[kbase + (wr*64 + fm*16 + (lane&15))*8];
      #pragma unroll
      for (int fm = 0; fm < 4; ++fm)
        #pragma unroll
        for (int fn = 0; fn < 4; ++fn)
          sacc[fm][fn] = __builtin_amdgcn_mfma_f32_16x16x32_bf16(kf[fm], qf[kk][fn], sacc[fm][fn], 0,0,0);
    }
    __syncthreads();  // all waves done reading K before P overwrites KP
    bool diag = (st == ti);
    #pragma unroll
    for (int fm = 0; fm < 4; ++fm) {
      int sb = wr*64 + fm*16 + ((lane>>4)<<2);   // s-local base (r=0); (sb&7) in {0,4}
      #pragma unroll
      for (int fn = 0; fn < 4; ++fn) {
        int tl = wc*64 + fn*16 + (lane&15);      // t-local
        float p[4];
        #pragma unroll
        for (int r = 0; r < 4; ++r) {
          float xv = sacc[fm][fn][r];
          float sv = silu_f(xv) * (1.f/2048.f);
          if (diag && (tl < sb + r)) sv = 0.f;   // zero where t < s
          p[r] = sv;
        }
        int a0 = (sb>>3)*1024 + tl*8 + (sb&7);   // P in A-frag layout [s/8][t][s%8]
        unsigned w0 = (unsigned)f2bf(p[0]) | ((unsigned)f2bf(p[1])<<16);
        unsigned w1 = (unsigned)f2bf(p[2]) | ((unsigned)f2bf(p[3])<<16);
        *(unsigned*)&KP[a0]   = w0;
        *(unsigned*)&KP[a0+2] = w1;
      }
    }
    __syncthreads();
    // O[t][h] += sum_s P[t][s] V[s][h]
    #pragma unroll
    for (int kk = 0; kk < 4; ++kk) {
      int kbase = (kk*4 + (lane>>4))*1024;
      short8 pa[4], vf[4];
      #pragma unroll
      for (int fm = 0; fm < 4; ++fm)
        pa[fm] = *(const short8*)&KP[kbase + (wr*64 + fm*16 + (lane&15))*8];
      #pragma unroll
      for (int fn = 0; fn < 4; ++fn)
        vf[fn] = *(const short8*)&VT[kbase + (wc*64 + fn*16 + (lane&15))*8];
      #pragma unroll
      for (int fm = 0; fm < 4; ++fm)
        #pragma unroll
        for (int fn = 0; fn < 4; ++fn)
          oacc[fm][fn] = __builtin_amdgcn_mfma_f32_16x16x32_bf16(pa[fm], vf[fn], oacc[fm][fn], 0,0,0);
    }
    __syncthreads();
  }
  // store O tile (bf16)
  #pragma unroll
  for (int fm = 0; fm < 4; ++fm) {
    int tl = wr*64 + fm*16 + ((lane>>4)<<2);
    #pragma unroll
    for (int fn = 0; fn < 4; ++fn) {
      int h = wc*64 + fn*16 + (lane&15);
      #pragma unroll
      for (int r = 0; r < 4; ++r)
        ob[(size_t)(t0 + tl + r)*D_ + h] = f2bf(oacc[fm][fn][r]);
    }
  }
}

// ---------------- LN over D of attn_out, times u -> y (bf16)
__global__ __launch_bounds__(256) void ln_mul_kernel(
    const unsigned short* __restrict__ ain, const float* __restrict__ gamma,
    const float* __restrict__ beta, const unsigned short* __restrict__ u,
    unsigned short* __restrict__ y)
{
  int row = blockIdx.x, tid = threadIdx.x;
  ushort4 av = ((const ushort4*)(ain + (size_t)row*D_))[tid];
  float v0 = bf2f(av.x), v1 = bf2f(av.y), v2 = bf2f(av.z), v3 = bf2f(av.w);
  float s = v0+v1+v2+v3;
  float ss = v0*v0+v1*v1+v2*v2+v3*v3;
  #pragma unroll
  for (int o = 32; o; o >>= 1) { s += __shfl_down(s,o); ss += __shfl_down(ss,o); }
  __shared__ float red[8];
  int lane = tid&63, wid = tid>>6;
  if (lane==0) { red[wid]=s; red[4+wid]=ss; }
  __syncthreads();
  s = red[0]+red[1]+red[2]+red[3];
  ss = red[4]+red[5]+red[6]+red[7];
  float mean = s * (1.f/D_);
  float var  = ss * (1.f/D_) - mean*mean;
  float rstd = rsqrtf(var + EPS_);
  float4 g = ((const float4*)gamma)[tid], b = ((const float4*)beta)[tid];
  ushort4 uu = ((const ushort4*)(u + (size_t)row*D_))[tid];
  ushort4 o;
  o.x = f2bf(bf2f(uu.x) * ((v0-mean)*rstd*g.x + b.x));
  o.y = f2bf(bf2f(uu.y) * ((v1-mean)*rstd*g.y + b.y));
  o.z = f2bf(bf2f(uu.z) * ((v2-mean)*rstd*g.z + b.z));
  o.w = f2bf(bf2f(uu.w) * ((v3-mean)*rstd*g.w + b.w));
  ((ushort4*)(y + (size_t)row*D_))[tid] = o;
}

extern "C" void kernel_launch(void* const* d_in, const int* in_sizes, int n_in,
                              void* d_out, int out_size, void* d_ws, size_t ws_size,
                              hipStream_t stream) {
  const float* inputs = (const float*)d_in[0];
  // d_in[1] = attention_mask (guaranteed causal tril; not read)
  const float* g_in = (const float*)d_in[2];
  const float* b_in = (const float*)d_in[3];
  const float* wu = (const float*)d_in[4];
  const float* wq = (const float*)d_in[5];
  const float* wk = (const float*)d_in[6];
  const float* wv = (const float*)d_in[7];
  const float* g_at = (const float*)d_in[8];
  const float* b_at = (const float*)d_in[9];
  const float* wo = (const float*)d_in[10];
  float* out = (float*)d_out;

  char* ws = (char*)d_ws;
  unsigned short* x   = (unsigned short*)(ws + ((size_t)0));        // 16 MiB (reused as y)
  unsigned short* q   = (unsigned short*)(ws + ((size_t)16<<20));   // 16 MiB
  unsigned short* k   = (unsigned short*)(ws + ((size_t)32<<20));   // 16 MiB
  unsigned short* u   = (unsigned short*)(ws + ((size_t)48<<20));   // 16 MiB
  unsigned short* vt  = (unsigned short*)(ws + ((size_t)64<<20));   // 16 MiB
  unsigned short* wt  = (unsigned short*)(ws + ((size_t)80<<20));   // 10 MiB (5 x 2 MiB: u,q,k,v,o)
  unsigned short* ao  = (unsigned short*)(ws + ((size_t)96<<20));   // 16 MiB attn_out bf16
  unsigned short* y = x;

  wt_kernel<<<dim3(16,16,5), 256, 0, stream>>>(wu, wq, wk, wv, wo, wt);
  ln_in_kernel<<<BL_, 256, 0, stream>>>(inputs, g_in, b_in, x);
  gemm8p<0><<<dim3(32,16), 512, 0, stream>>>(x, wt, u, q, k, vt, nullptr, nullptr);
  attn_kernel<<<dim3(16,32), 256, 0, stream>>>(q, k, vt, ao);
  ln_mul_kernel<<<BL_, 256, 0, stream>>>(ao, g_at, b_at, u, y);
  gemm8p<1><<<dim3(32,8), 512, 0, stream>>>(y, wt + (size_t)4*D_*D_,
                                            nullptr, nullptr, nullptr, nullptr, inputs, out);
}

// Round 6
// 295.392 us; speedup vs baseline: 1.3947x; 1.3947x over previous
//
#include <hip/hip_runtime.h>
#include <hip/hip_bf16.h>
#include <stdint.h>

#define D_    1024
#define L_    2048
#define B_    4
#define NHEAD 8
#define HDIM  128
#define BL_   (B_*L_)   // 8192
#define EPS_  1e-6f

typedef __attribute__((ext_vector_type(8))) short short8;
typedef __attribute__((ext_vector_type(4))) float f32x4;

__device__ __forceinline__ unsigned short f2bf(float f) {
  unsigned u = __builtin_bit_cast(unsigned, f);
  unsigned r = 0x7fffu + ((u >> 16) & 1u);
  return (unsigned short)((u + r) >> 16);
}
__device__ __forceinline__ float bf2f(unsigned short h) {
  return __builtin_bit_cast(float, ((unsigned)h) << 16);
}
__device__ __forceinline__ float silu_f(float x) { return x / (1.f + __expf(-x)); }

// async global->LDS, 16B per lane; LDS dest is wave-uniform base + lane*16
__device__ __forceinline__ void gll16(const void* g, void* l) {
  auto gp = reinterpret_cast<const __attribute__((address_space(1))) unsigned*>(
      reinterpret_cast<uintptr_t>(g));
  auto lp = reinterpret_cast<__attribute__((address_space(3))) unsigned*>(
      (unsigned)reinterpret_cast<uintptr_t>(l));
  __builtin_amdgcn_global_load_lds(gp, lp, 16, 0, 0);
}

// ---------------- weight transpose + cast: w[1024][1024] f32 -> wt[1024][1024] bf16 (wt = w^T)
__global__ __launch_bounds__(256) void wt_kernel(
    const float* __restrict__ wu, const float* __restrict__ wq,
    const float* __restrict__ wk, const float* __restrict__ wv,
    const float* __restrict__ wo, unsigned short* __restrict__ wt)
{
  __shared__ float t[64][65];
  int mat = blockIdx.z;
  const float* src = mat==0?wu: mat==1?wq: mat==2?wk: mat==3?wv: wo;
  unsigned short* dst = wt + (size_t)mat*D_*D_;
  int r0 = blockIdx.y*64, c0 = blockIdx.x*64;
  int tid = threadIdx.x;
  for (int i = 0; i < 16; ++i) {
    int e = i*256 + tid; int r = e>>6, c = e&63;
    t[r][c] = src[(size_t)(r0+r)*D_ + c0 + c];
  }
  __syncthreads();
  for (int i = 0; i < 16; ++i) {
    int e = i*256 + tid; int r = e>>6, c = e&63;
    dst[(size_t)(c0+r)*D_ + r0 + c] = f2bf(t[c][r]);
  }
}

// ---------------- input LN -> bf16 x
__global__ __launch_bounds__(256) void ln_in_kernel(
    const float* __restrict__ in, const float* __restrict__ gamma,
    const float* __restrict__ beta, unsigned short* __restrict__ x)
{
  int row = blockIdx.x, tid = threadIdx.x;
  float4 v = ((const float4*)(in + (size_t)row*D_))[tid];
  float s = v.x+v.y+v.z+v.w;
  float ss = v.x*v.x + v.y*v.y + v.z*v.z + v.w*v.w;
  #pragma unroll
  for (int o = 32; o; o >>= 1) { s += __shfl_down(s,o); ss += __shfl_down(ss,o); }
  __shared__ float red[8];
  int lane = tid&63, wid = tid>>6;
  if (lane==0) { red[wid]=s; red[4+wid]=ss; }
  __syncthreads();
  s = red[0]+red[1]+red[2]+red[3];
  ss = red[4]+red[5]+red[6]+red[7];
  float mean = s * (1.f/D_);
  float var  = ss * (1.f/D_) - mean*mean;
  float rstd = rsqrtf(var + EPS_);
  float4 g = ((const float4*)gamma)[tid], b = ((const float4*)beta)[tid];
  ushort4 o;
  o.x = f2bf((v.x-mean)*rstd*g.x + b.x);
  o.y = f2bf((v.y-mean)*rstd*g.y + b.y);
  o.z = f2bf((v.z-mean)*rstd*g.z + b.z);
  o.w = f2bf((v.w-mean)*rstd*g.w + b.w);
  ((ushort4*)(x + (size_t)row*D_))[tid] = o;
}

// ---------------- 256x(BN) phased GEMM, C = A[M][1024] * Bt[cols][1024]^T
// 8 waves, BK=32 per phase, 4-slice LDS ring (2 K-tiles), counted vmcnt (T3+T4), setprio (T5).
// MODE 0: BN=256, silu epilogue -> u/q/k bf16 + v transposed; MODE 1: BN=128, acc+resid f32.
template<int MODE>
__global__ __launch_bounds__(512, 2) void gemm8p(
    const unsigned short* __restrict__ A, const unsigned short* __restrict__ Bt,
    unsigned short* __restrict__ o_u, unsigned short* __restrict__ o_q,
    unsigned short* __restrict__ o_k, unsigned short* __restrict__ o_vt,
    const float* __restrict__ resid, float* __restrict__ o_f)
{
  constexpr int BN  = (MODE==0) ? 256 : 128;
  constexpr int WN  = (MODE==0) ? 4 : 2;       // waves along N
  constexpr int WTM = (MODE==0) ? 128 : 64;    // wave tile rows (256/WM)
  constexpr int MF  = WTM/16;                  // m-frags per wave: 8 or 4
  constexpr int BNS = BN*32;                   // B slice ushorts (BK=32)
  constexpr int BOFF = 32768;                  // A region: 4 slices * 8192
  constexpr int RG  = BN/64;                   // row-groups per kk8 in B slice
  constexpr int NBCHW = (BNS/512)/8;           // B chunks per wave
  const int K = 1024;

  __shared__ unsigned short lds[BOFF + 4*BNS];

  int lane = threadIdx.x & 63, wid = threadIdx.x >> 6;
  int wr = wid / WN, wc = wid % WN;
  int m0 = blockIdx.x * 256;
  int n0 = blockIdx.y * BN;
  const unsigned short* Ab = A + (size_t)m0*K;
  const unsigned short* Bb = Bt + (size_t)n0*K;

  f32x4 acc[MF][4] = {};

  auto stage = [&](int dbs, int k0) {
    #pragma unroll
    for (int j = 0; j < 2; ++j) {
      int c = wid*2 + j;                 // 16 A chunks
      int row = (c&3)*64 + lane;
      int kof = k0 + ((c>>2)<<3);
      gll16(Ab + (size_t)row*K + kof, &lds[dbs*8192 + c*512]);
    }
    #pragma unroll
    for (int j = 0; j < NBCHW; ++j) {
      int c = wid*NBCHW + j;             // BNS/512 B chunks
      int kk8 = c / RG, rg = c % RG;
      int row = rg*64 + lane;
      int kof = k0 + (kk8<<3);
      gll16(Bb + (size_t)row*K + kof, &lds[BOFF + dbs*BNS + c*512]);
    }
  };

  // prologue: stage phases 0..3 (K-tiles 0,1), wait for phase 0's slice
  #pragma unroll
  for (int gp = 0; gp < 4; ++gp) stage(gp, gp*32);
  if constexpr (MODE==0) asm volatile("s_waitcnt vmcnt(12)" ::: "memory");
  else                   asm volatile("s_waitcnt vmcnt(9)"  ::: "memory");
  __builtin_amdgcn_s_barrier();

  auto do_phase = [&](int g, bool dostage) {
    const int bs = g & 3;
    const int kk4 = lane>>4, l15 = lane&15;
    short8 af[MF], bfr[4];
    const int ab = bs*8192 + kk4*2048 + (wr*WTM + l15)*8;
    #pragma unroll
    for (int m = 0; m < MF; ++m) af[m] = *(const short8*)&lds[ab + m*128];
    const int bb = BOFF + bs*BNS + kk4*(BN*8) + (wc*64 + l15)*8;
    #pragma unroll
    for (int n = 0; n < 4; ++n) bfr[n] = *(const short8*)&lds[bb + n*128];
    if (dostage) {
      int tp = g + 3;
      int k0 = (tp < 32 ? tp : 31) * 32;   // clamp SOURCE only; dest region stays tp&3
      stage(tp & 3, k0);
    }
    __builtin_amdgcn_sched_barrier(0);
    __builtin_amdgcn_s_barrier();
    asm volatile("s_waitcnt lgkmcnt(0)" ::: "memory");
    __builtin_amdgcn_sched_barrier(0);
    __builtin_amdgcn_s_setprio(1);
    #pragma unroll
    for (int m = 0; m < MF; ++m)
      #pragma unroll
      for (int n = 0; n < 4; ++n)
        acc[m][n] = __builtin_amdgcn_mfma_f32_16x16x32_bf16(af[m], bfr[n], acc[m][n], 0,0,0);
    __builtin_amdgcn_s_setprio(0);
    if constexpr (MODE==0) asm volatile("s_waitcnt vmcnt(8)" ::: "memory");
    else                   asm volatile("s_waitcnt vmcnt(6)" ::: "memory");
    __builtin_amdgcn_sched_barrier(0);
    __builtin_amdgcn_s_barrier();
  };

  do_phase(0, false);
  #pragma unroll
  for (int g = 1; g < 32; ++g) do_phase(g, true);

  if constexpr (MODE == 0) {
    int mat = n0 >> 10;
    int jb = n0 & 1023;
    #pragma unroll
    for (int m = 0; m < MF; ++m) {
      int t_ = m0 + wr*WTM + m*16 + ((lane>>4)<<2);
      #pragma unroll
      for (int n = 0; n < 4; ++n) {
        int jj = jb + wc*64 + n*16 + (lane&15);
        float p0 = silu_f(acc[m][n][0]);
        float p1 = silu_f(acc[m][n][1]);
        float p2 = silu_f(acc[m][n][2]);
        float p3 = silu_f(acc[m][n][3]);
        if (mat == 3) {
          int b = t_ >> 11, tt = t_ & 2047;
          int nn = jj >> 7, h = jj & 127;
          ushort4 pk;
          pk.x = f2bf(p0); pk.y = f2bf(p1); pk.z = f2bf(p2); pk.w = f2bf(p3);
          *(ushort4*)&o_vt[(((size_t)(b*NHEAD+nn))*HDIM + h)*L_ + tt] = pk;
        } else {
          unsigned short* dst = mat==0 ? o_u : (mat==1 ? o_q : o_k);
          dst[(size_t)(t_+0)*D_ + jj] = f2bf(p0);
          dst[(size_t)(t_+1)*D_ + jj] = f2bf(p1);
          dst[(size_t)(t_+2)*D_ + jj] = f2bf(p2);
          dst[(size_t)(t_+3)*D_ + jj] = f2bf(p3);
        }
      }
    }
  } else {
    #pragma unroll
    for (int m = 0; m < MF; ++m) {
      int t_ = m0 + wr*WTM + m*16 + ((lane>>4)<<2);
      #pragma unroll
      for (int n = 0; n < 4; ++n) {
        int jj = n0 + wc*64 + n*16 + (lane&15);
        #pragma unroll
        for (int r = 0; r < 4; ++r)
          o_f[(size_t)(t_+r)*D_ + jj] = acc[m][n][r] + resid[(size_t)(t_+r)*D_ + jj];
      }
    }
  }
}

// ---------------- causal pointwise-silu attention
// paired t-tiles (p, 15-p) per block -> uniform 17 s-iterations; 256 blocks = 1/CU.
// XCD placement: grid (8,32), blockIdx.x = bh%8 -> XCD x serves heads {x, x+8, x+16, x+24};
// their K/V (4 x 1 MB) fit the 4 MiB per-XCD L2, so staging re-reads are L2 hits.
// Per s-iter: QK^T -> P-write -> read ALL P/V frags to regs -> barrier ->
//   issue next K/V stage (async) -> PV MFMAs (hide staging) -> sync.
__global__ __launch_bounds__(256, 1) void attn_kernel(
    const unsigned short* __restrict__ gq, const unsigned short* __restrict__ gk,
    const unsigned short* __restrict__ gvt, unsigned short* __restrict__ attn_out)
{
  __shared__ unsigned short KP[16384];  // K tile / P tile: [x/8][128][8]
  __shared__ unsigned short VT[16384];  // V^T tile: [s/8][h(128)][8]
  int bh = ((int)blockIdx.y & 3) * 8 + (int)blockIdx.x;  // x == bh%8 == XCD
  int pair = (int)blockIdx.y >> 2;                        // 0..7
  int b = bh >> 3, n = bh & 7;
  const unsigned short* qb = gq + (size_t)b*L_*D_ + n*HDIM;
  const unsigned short* kb = gk + (size_t)b*L_*D_ + n*HDIM;
  const unsigned short* vb = gvt + (size_t)bh*HDIM*L_;
  unsigned short* ob = attn_out + (size_t)b*L_*D_ + n*HDIM;
  int lane = threadIdx.x & 63, wid = threadIdx.x >> 6;
  int wr = wid >> 1, wc = wid & 1;

  for (int half = 0; half < 2; ++half) {
    int ti = half ? 15 - pair : pair;
    int t0 = ti * 128;
    // stage Q tile into KP, hoist B-fragments to registers
    #pragma unroll
    for (int i = 0; i < 8; ++i) {
      int c = wid*8 + i;
      int row = ((c&1)<<6) + lane;
      int kof = (c>>1)<<3;
      gll16(qb + (size_t)(t0+row)*D_ + kof, &KP[c*512]);
    }
    __syncthreads();
    short8 qf[4][4];
    #pragma unroll
    for (int kk = 0; kk < 4; ++kk) {
      int kbase = (kk*4 + (lane>>4))*1024;
      #pragma unroll
      for (int fn = 0; fn < 4; ++fn)
        qf[kk][fn] = *(const short8*)&KP[kbase + (wc*64 + fn*16 + (lane&15))*8];
    }
    __syncthreads();   // Q reads done before K stage overwrites KP
    // prologue: stage K_0, V_0
    #pragma unroll
    for (int i = 0; i < 8; ++i) {
      int c = wid*8 + i;
      int row = ((c&1)<<6) + lane;
      int kof = (c>>1)<<3;
      gll16(kb + (size_t)row*D_ + kof, &KP[c*512]);
      gll16(vb + (size_t)row*L_ + kof, &VT[c*512]);
    }
    __syncthreads();   // vmcnt(0) + barrier: K_0/V_0 ready

    f32x4 oacc[4][4] = {};
    for (int st = 0; st <= ti; ++st) {
      // S^T[s][t] = sum_h K[s][h] Q[t][h]
      f32x4 sacc[4][4] = {};
      #pragma unroll
      for (int kk = 0; kk < 4; ++kk) {
        int kbase = (kk*4 + (lane>>4))*1024;
        short8 kf[4];
        #pragma unroll
        for (int fm = 0; fm < 4; ++fm)
          kf[fm] = *(const short8*)&KP[kbase + (wr*64 + fm*16 + (lane&15))*8];
        #pragma unroll
        for (int fm = 0; fm < 4; ++fm)
          #pragma unroll
          for (int fn = 0; fn < 4; ++fn)
            sacc[fm][fn] = __builtin_amdgcn_mfma_f32_16x16x32_bf16(kf[fm], qf[kk][fn], sacc[fm][fn], 0,0,0);
      }
      __syncthreads();  // all waves done reading K before P overwrites KP
      bool diag = (st == ti);
      #pragma unroll
      for (int fm = 0; fm < 4; ++fm) {
        int sb = wr*64 + fm*16 + ((lane>>4)<<2);   // s-local base (r=0); (sb&7) in {0,4}
        #pragma unroll
        for (int fn = 0; fn < 4; ++fn) {
          int tl = wc*64 + fn*16 + (lane&15);      // t-local
          float p[4];
          #pragma unroll
          for (int r = 0; r < 4; ++r) {
            float xv = sacc[fm][fn][r];
            float sv = silu_f(xv) * (1.f/2048.f);
            if (diag && (tl < sb + r)) sv = 0.f;   // zero where t < s
            p[r] = sv;
          }
          int a0 = (sb>>3)*1024 + tl*8 + (sb&7);   // P in A-frag layout [s/8][t][s%8]
          unsigned w0 = (unsigned)f2bf(p[0]) | ((unsigned)f2bf(p[1])<<16);
          unsigned w1 = (unsigned)f2bf(p[2]) | ((unsigned)f2bf(p[3])<<16);
          *(unsigned*)&KP[a0]   = w0;
          *(unsigned*)&KP[a0+2] = w1;
        }
      }
      __syncthreads();  // P visible to all waves
      // read ALL P and V fragments to registers, then free the buffers
      short8 pa[4][4], vf[4][4];
      #pragma unroll
      for (int kk = 0; kk < 4; ++kk) {
        int kbase = (kk*4 + (lane>>4))*1024;
        #pragma unroll
        for (int fm = 0; fm < 4; ++fm)
          pa[kk][fm] = *(const short8*)&KP[kbase + (wr*64 + fm*16 + (lane&15))*8];
        #pragma unroll
        for (int fn = 0; fn < 4; ++fn)
          vf[kk][fn] = *(const short8*)&VT[kbase + (wc*64 + fn*16 + (lane&15))*8];
      }
      __syncthreads();  // lgkm drained: every wave holds P,V in regs; KP/VT dead
      if (st < ti) {
        int s0 = (st+1)*128;
        #pragma unroll
        for (int i = 0; i < 8; ++i) {
          int c = wid*8 + i;
          int row = ((c&1)<<6) + lane;
          int kof = (c>>1)<<3;
          gll16(kb + (size_t)(s0+row)*D_ + kof, &KP[c*512]);
          gll16(vb + (size_t)row*L_ + s0 + kof, &VT[c*512]);
        }
      }
      __builtin_amdgcn_sched_barrier(0);  // keep stage-issue ahead of the MFMA block
      // O[t][h] += sum_s P[t][s] V[s][h]  (staging latency hides under these)
      #pragma unroll
      for (int kk = 0; kk < 4; ++kk)
        #pragma unroll
        for (int fm = 0; fm < 4; ++fm)
          #pragma unroll
          for (int fn = 0; fn < 4; ++fn)
            oacc[fm][fn] = __builtin_amdgcn_mfma_f32_16x16x32_bf16(pa[kk][fm], vf[kk][fn], oacc[fm][fn], 0,0,0);
      __syncthreads();  // vmcnt(0)+barrier: next K/V tile ready
    }
    // store O tile (bf16)
    #pragma unroll
    for (int fm = 0; fm < 4; ++fm) {
      int tl = wr*64 + fm*16 + ((lane>>4)<<2);
      #pragma unroll
      for (int fn = 0; fn < 4; ++fn) {
        int h = wc*64 + fn*16 + (lane&15);
        #pragma unroll
        for (int r = 0; r < 4; ++r)
          ob[(size_t)(t0 + tl + r)*D_ + h] = f2bf(oacc[fm][fn][r]);
      }
    }
  }
}

// ---------------- LN over D of attn_out, times u -> y (bf16)
__global__ __launch_bounds__(256) void ln_mul_kernel(
    const unsigned short* __restrict__ ain, const float* __restrict__ gamma,
    const float* __restrict__ beta, const unsigned short* __restrict__ u,
    unsigned short* __restrict__ y)
{
  int row = blockIdx.x, tid = threadIdx.x;
  ushort4 av = ((const ushort4*)(ain + (size_t)row*D_))[tid];
  float v0 = bf2f(av.x), v1 = bf2f(av.y), v2 = bf2f(av.z), v3 = bf2f(av.w);
  float s = v0+v1+v2+v3;
  float ss = v0*v0+v1*v1+v2*v2+v3*v3;
  #pragma unroll
  for (int o = 32; o; o >>= 1) { s += __shfl_down(s,o); ss += __shfl_down(ss,o); }
  __shared__ float red[8];
  int lane = tid&63, wid = tid>>6;
  if (lane==0) { red[wid]=s; red[4+wid]=ss; }
  __syncthreads();
  s = red[0]+red[1]+red[2]+red[3];
  ss = red[4]+red[5]+red[6]+red[7];
  float mean = s * (1.f/D_);
  float var  = ss * (1.f/D_) - mean*mean;
  float rstd = rsqrtf(var + EPS_);
  float4 g = ((const float4*)gamma)[tid], b = ((const float4*)beta)[tid];
  ushort4 uu = ((const ushort4*)(u + (size_t)row*D_))[tid];
  ushort4 o;
  o.x = f2bf(bf2f(uu.x) * ((v0-mean)*rstd*g.x + b.x));
  o.y = f2bf(bf2f(uu.y) * ((v1-mean)*rstd*g.y + b.y));
  o.z = f2bf(bf2f(uu.z) * ((v2-mean)*rstd*g.z + b.z));
  o.w = f2bf(bf2f(uu.w) * ((v3-mean)*rstd*g.w + b.w));
  ((ushort4*)(y + (size_t)row*D_))[tid] = o;
}

extern "C" void kernel_launch(void* const* d_in, const int* in_sizes, int n_in,
                              void* d_out, int out_size, void* d_ws, size_t ws_size,
                              hipStream_t stream) {
  const float* inputs = (const float*)d_in[0];
  // d_in[1] = attention_mask (guaranteed causal tril; not read)
  const float* g_in = (const float*)d_in[2];
  const float* b_in = (const float*)d_in[3];
  const float* wu = (const float*)d_in[4];
  const float* wq = (const float*)d_in[5];
  const float* wk = (const float*)d_in[6];
  const float* wv = (const float*)d_in[7];
  const float* g_at = (const float*)d_in[8];
  const float* b_at = (const float*)d_in[9];
  const float* wo = (const float*)d_in[10];
  float* out = (float*)d_out;

  char* ws = (char*)d_ws;
  unsigned short* x   = (unsigned short*)(ws + ((size_t)0));        // 16 MiB (reused as y)
  unsigned short* q   = (unsigned short*)(ws + ((size_t)16<<20));   // 16 MiB
  unsigned short* k   = (unsigned short*)(ws + ((size_t)32<<20));   // 16 MiB
  unsigned short* u   = (unsigned short*)(ws + ((size_t)48<<20));   // 16 MiB
  unsigned short* vt  = (unsigned short*)(ws + ((size_t)64<<20));   // 16 MiB
  unsigned short* wt  = (unsigned short*)(ws + ((size_t)80<<20));   // 10 MiB (5 x 2 MiB: u,q,k,v,o)
  unsigned short* ao  = (unsigned short*)(ws + ((size_t)96<<20));   // 16 MiB attn_out bf16
  unsigned short* y = x;

  wt_kernel<<<dim3(16,16,5), 256, 0, stream>>>(wu, wq, wk, wv, wo, wt);
  ln_in_kernel<<<BL_, 256, 0, stream>>>(inputs, g_in, b_in, x);
  gemm8p<0><<<dim3(32,16), 512, 0, stream>>>(x, wt, u, q, k, vt, nullptr, nullptr);
  attn_kernel<<<dim3(8,32), 256, 0, stream>>>(q, k, vt, ao);
  ln_mul_kernel<<<BL_, 256, 0, stream>>>(ao, g_at, b_at, u, y);
  gemm8p<1><<<dim3(32,8), 512, 0, stream>>>(y, wt + (size_t)4*D_*D_,
                                            nullptr, nullptr, nullptr, nullptr, inputs, out);
}